// Round 11
// baseline (113.729 us; speedup 1.0000x reference)
//
#include <hip/hip_runtime.h>
#include <stdint.h>

typedef uint16_t u16;
typedef uint32_t u32;
typedef __attribute__((ext_vector_type(8))) _Float16 f16x8;
typedef __attribute__((ext_vector_type(4))) _Float16 f16x4;
typedef __attribute__((ext_vector_type(4))) float f32x4;
typedef __attribute__((ext_vector_type(2))) uint32_t u32x2;

#define NB 2
#define NT 2048
#define NC 1024
#define NH 16
#define ND 64
#define NM (NB*NT)   // 4096 rows of x
#define LOG2E 1.44269504088896340736f
#define PSTRIDE 4608   // u16 elems per partial slot: 64*64 O + 64 m(f32) + 64 l(f32) + pad

__device__ __forceinline__ u16 f2h(float f) {
  _Float16 h = (_Float16)f;   // RNE
  return __builtin_bit_cast(u16, h);
}

// ---------------- f32 -> f16 convert, 4 elems/thread ----------------
__global__ __launch_bounds__(256) void cvt_kernel(const float* __restrict__ src,
                                                  u16* __restrict__ dst, int n4) {
  int i = blockIdx.x * 256 + threadIdx.x;
  if (i >= n4) return;
  float4 v = ((const float4*)src)[i];
  ushort4 o;
  o.x = f2h(v.x); o.y = f2h(v.y); o.z = f2h(v.z); o.w = f2h(v.w);
  ((ushort4*)dst)[i] = o;
}

// 4 weights -> one contiguous f16 region (Wq|Wk|Wv|Wproj)
__global__ __launch_bounds__(256) void cvtw_kernel(const float* __restrict__ w0,
                                                   const float* __restrict__ w1,
                                                   const float* __restrict__ w2,
                                                   const float* __restrict__ w3,
                                                   u16* __restrict__ dst) {
  int i = blockIdx.x * 256 + threadIdx.x;       // 0 .. 4*NC*NC/4
  int which = i >> 18;                          // NC*NC/4 = 262144
  const float* src = (which == 0) ? w0 : (which == 1) ? w1 : (which == 2) ? w2 : w3;
  int j = i & 262143;
  float4 v = ((const float4*)src)[j];
  ushort4 o;
  o.x = f2h(v.x); o.y = f2h(v.y); o.z = f2h(v.z); o.w = f2h(v.w);
  ((ushort4*)dst)[i] = o;
}

// ---------------- async global->LDS 16B ----------------
__device__ __forceinline__ void gload16(const void* g, void* l) {
  __builtin_amdgcn_global_load_lds(
      (const __attribute__((address_space(1))) void*)g,
      (__attribute__((address_space(3))) void*)l, 16, 0, 0);
}

// ---------------- GEMM, both operands k-major (C[m][n] = sum_k A[m][k]*B[n][k]) ---
// Double-buffered staging + XOR-swizzled LDS (conflict-free ds_read_b128).
// EPI 0: QKV epilogue, LDS re-tiled + coalesced 16B stores.
// EPI 1: f32 row-major output.
template<int EPI>
__global__ __launch_bounds__(256) void gemm_bt(const u16* __restrict__ A,
                                               const u16* __restrict__ Bw,
                                               int K, int N,
                                               u16* __restrict__ oq, u16* __restrict__ okk,
                                               u16* __restrict__ ovt,
                                               float* __restrict__ of) {
  __shared__ __align__(16) u16 SH[4*128*64];   // 64 KB: A dbuf | B dbuf
  u16* Al = SH;
  u16* Bl = SH + 2*128*64;
  const int tid = threadIdx.x, lane = tid & 63, wid = tid >> 6;
  const int g = lane >> 4, qq = lane & 15;
  const int wm = wid >> 1, wn = wid & 1;
  const int m0 = blockIdx.y * 128, n0 = blockIdx.x * 128;
  const int srow = lane >> 3;            // row within an 8-row staging issue
  const int scol8 = (lane & 7) ^ srow;   // pre-swizzled 16B-slot in global source

  f32x4 acc[4][4] = {};
  const int nk = K >> 6;

  #pragma unroll
  for (int pp = 0; pp < 4; ++pp) {
    int r = wid*32 + pp*8;
    gload16(A  + (size_t)(m0 + r + srow)*K + scol8*8, &Al[r*64]);
    gload16(Bw + (size_t)(n0 + r + srow)*K + scol8*8, &Bl[r*64]);
  }

  for (int kt = 0; kt < nk; ++kt) {
    const int cur = kt & 1;
    __syncthreads();
    if (kt + 1 < nk) {
      const int k1 = (kt + 1) << 6;
      #pragma unroll
      for (int pp = 0; pp < 4; ++pp) {
        int r = wid*32 + pp*8;
        gload16(A  + (size_t)(m0 + r + srow)*K + k1 + scol8*8, &Al[(cur^1)*8192 + r*64]);
        gload16(Bw + (size_t)(n0 + r + srow)*K + k1 + scol8*8, &Bl[(cur^1)*8192 + r*64]);
      }
    }
    #pragma unroll
    for (int kk = 0; kk < 2; ++kk) {
      f16x8 af[4], bfr[4];
      #pragma unroll
      for (int mt = 0; mt < 4; ++mt) {
        int row = wm*64 + mt*16 + qq;
        af[mt] = *(const f16x8*)&Al[cur*8192 + row*64 + (((kk*4 + g) ^ (qq & 7))*8)];
      }
      #pragma unroll
      for (int nt = 0; nt < 4; ++nt) {
        int row = wn*64 + nt*16 + qq;
        bfr[nt] = *(const f16x8*)&Bl[cur*8192 + row*64 + (((kk*4 + g) ^ (qq & 7))*8)];
      }
      #pragma unroll
      for (int mt = 0; mt < 4; ++mt)
        #pragma unroll
        for (int nt = 0; nt < 4; ++nt)
          acc[mt][nt] = __builtin_amdgcn_mfma_f32_16x16x32_f16(af[mt], bfr[nt], acc[mt][nt], 0, 0, 0);
    }
  }

  if (EPI == 0) {
    __syncthreads();
    u16* reg = SH + wid*4096;
    const int sel = n0 >> 10;
    const int h = ((n0 & 1023) >> 6) + wn;
    const int bq = m0 >> 11;

    if (sel < 2) {
      const float scale = (sel == 0) ? 0.125f*LOG2E : 1.0f;
      #pragma unroll
      for (int mt = 0; mt < 4; ++mt)
        #pragma unroll
        for (int r = 0; r < 4; ++r) {
          int mloc = mt*16 + g*4 + r;
          #pragma unroll
          for (int nt = 0; nt < 4; ++nt) {
            int d = nt*16 + qq;
            reg[mloc*64 + (d ^ (g << 4))] = f2h(acc[mt][nt][r] * scale);
          }
        }
      u16* dst = (sel == 0) ? oq : okk;
      const int slot = lane & 7;
      #pragma unroll
      for (int i = 0; i < 8; ++i) {
        int row = i*8 + (lane >> 3);
        int physslot = slot ^ (((row >> 2) & 3) << 1);
        f16x8 vvv = *(const f16x8*)&reg[row*64 + physslot*8];
        int m = m0 + wm*64 + row;
        int t = m & (NT-1);
        *(f16x8*)(dst + (((size_t)(bq*NH + h)*NT + t)*ND) + slot*8) = vvv;
      }
    } else {
      #pragma unroll
      for (int nt = 0; nt < 4; ++nt) {
        int d = nt*16 + qq;
        int f = (d & 7) << 3;
        #pragma unroll
        for (int mt = 0; mt < 4; ++mt)
          #pragma unroll
          for (int rp = 0; rp < 2; ++rp) {
            int r = rp*2;
            int mloc = mt*16 + g*4 + r;
            u32 pk = (u32)f2h(acc[mt][nt][r]) | ((u32)f2h(acc[mt][nt][r+1]) << 16);
            *(u32*)&reg[d*64 + (mloc ^ f)] = pk;
          }
      }
      const int slot = lane & 7;
      const int t0 = m0 + wm*64;
      #pragma unroll
      for (int i = 0; i < 8; ++i) {
        int d = i*8 + (lane >> 3);
        int physslot = slot ^ (d & 7);
        f16x8 vvv = *(const f16x8*)&reg[d*64 + physslot*8];
        int t = (t0 & (NT-1)) + slot*8;
        *(f16x8*)(ovt + ((size_t)(bq*NH + h)*ND + d)*NT + t) = vvv;
      }
    }
  } else {
    #pragma unroll
    for (int mt = 0; mt < 4; ++mt)
      #pragma unroll
      for (int r = 0; r < 4; ++r) {
        int m = m0 + wm*64 + mt*16 + g*4 + r;
        #pragma unroll
        for (int nt = 0; nt < 4; ++nt) {
          int n = n0 + wn*64 + nt*16 + qq;
          of[(size_t)m*N + n] = acc[mt][nt][r];
        }
      }
  }
}

// ---------------- flash attention: split-kv + in-register P->PV (K=16 MFMA) ---
// Swapped QK^T leaves S for q=qq at kv=nt*16+4g+r per lane — exactly the
// B-fragment layout of mfma_f32_16x16x16_f16. P is cvt_pkrtz'd in place and fed
// straight to PV as B; A = V^T fragments (ds_read_b64). No P LDS round-trip,
// no cross-lane ops in softmax (alpha, 1/l are per-lane scalars; l via ones-MFMA).
// O^T C-layout: O[q=qq][d = dt*16 + g*4 + r].
#define IT(q,s,c,m) ((u32)(q) | ((u32)(s)<<8) | ((u32)(c)<<16) | ((u32)(m)<<24))
__global__ __launch_bounds__(256, 5) void attn_kernel(const u16* __restrict__ q,
                                                      const u16* __restrict__ k,
                                                      const u16* __restrict__ vt,
                                                      u16* __restrict__ y,
                                                      u16* __restrict__ part) {
  static const u32 items[48] = {
    IT(15,0,16,0), IT(30,0,16,1), IT(31,0,16,1), IT(31,16,16,2),
    IT(14,0,15,0), IT(28,0,15,1), IT(29,0,15,1), IT(29,15,15,2), IT(30,16,15,2),
    IT(13,0,14,0), IT(26,0,14,1), IT(27,0,14,1), IT(27,14,14,2), IT(28,15,14,2),
    IT(12,0,13,0), IT(24,0,13,1), IT(25,0,13,1), IT(25,13,13,2), IT(26,14,13,2),
    IT(11,0,12,0), IT(22,0,12,1), IT(23,0,12,1), IT(23,12,12,2), IT(24,13,12,2),
    IT(10,0,11,0), IT(20,0,11,1), IT(21,0,11,1), IT(21,11,11,2), IT(22,12,11,2),
    IT( 9,0,10,0), IT(18,0,10,1), IT(19,0,10,1), IT(19,10,10,2), IT(20,11,10,2),
    IT( 8,0, 9,0), IT(16,0, 9,1), IT(17,0, 9,1), IT(17, 9, 9,2), IT(18,10, 9,2),
    IT( 7,0, 8,0), IT(16,9, 8,2),
    IT( 6,0, 7,0), IT( 5,0, 6,0), IT( 4,0, 5,0), IT( 3,0, 4,0),
    IT( 2,0, 3,0), IT( 1,0, 2,0), IT( 0,0, 1,0)
  };
  __shared__ __align__(16) u16 Kl[2][64*64];
  __shared__ __align__(16) u16 Vl[2][64*64];
  const int tid = threadIdx.x, lane = tid & 63, wid = tid >> 6;
  const int g = lane >> 4, qq = lane & 15;
  const int bh = blockIdx.x;
  const u32 it = items[blockIdx.y];
  const int qtile = it & 255;
  const int ks = (it >> 8) & 255;
  const int kc = (it >> 16) & 255;
  const int mode = it >> 24;
  const int qs = qtile * 64;
  const u16* qp = q  + (size_t)bh*NT*ND;
  const u16* kp = k  + (size_t)bh*NT*ND;
  const u16* vp = vt + (size_t)bh*ND*NT;
  const int b = bh >> 4, h = bh & 15;
  const int srow = lane >> 3;
  const int scol8 = (lane & 7) ^ (srow & 7);  // pre-swizzled 16B-slot in global source

  // Q B-fragment in registers (col q = qs + wid*16 + qq)
  f16x8 aq[2];
  {
    int t = qs + wid*16 + qq;
    #pragma unroll
    for (int c = 0; c < 2; ++c)
      aq[c] = *(const f16x8*)(qp + (size_t)t*ND + c*32 + 8*g);
  }

  f16x4 ones4;
  #pragma unroll
  for (int i = 0; i < 4; ++i) ones4[i] = (_Float16)1.0f;

  f32x4 accO[4] = {};               // O[q = qq][d = dt*16 + g*4 + r]
  f32x4 accS = {};                  // l[q = qq] (ones-MFMA; all 4 regs equal)
  float m_run = -1e30f;             // per-lane, q = qq

  // prologue: stage kv tile ks into buf 0
  #pragma unroll
  for (int pp = 0; pp < 2; ++pp) {
    int issue = wid*2 + pp;
    int row = issue*8 + srow;
    gload16(kp + (size_t)(ks*64 + row)*ND + scol8*8, &Kl[0][issue*512]);
    gload16(vp + (size_t)row*NT + ks*64 + scol8*8, &Vl[0][issue*512]);
  }

  for (int kt = ks; kt < ks + kc; ++kt) {
    const int kvs = kt*64;
    const int cur = (kt - ks) & 1;
    __syncthreads();                // stage(kt) drained; buf cur^1 free

    if (kt + 1 < ks + kc) {         // stage next tile under compute(kt)
      const int kvs2 = kvs + 64;
      #pragma unroll
      for (int pp = 0; pp < 2; ++pp) {
        int issue = wid*2 + pp;
        int row = issue*8 + srow;
        gload16(kp + (size_t)(kvs2 + row)*ND + scol8*8, &Kl[cur^1][issue*512]);
        gload16(vp + (size_t)row*NT + kvs2 + scol8*8, &Vl[cur^1][issue*512]);
      }
    }

    // S^T = K Q^T: sacc[nt][r]: kv = kvs+nt*16+g*4+r, q = qs+wid*16+qq
    f32x4 sacc[4] = {};
    __builtin_amdgcn_s_setprio(1);
    #pragma unroll
    for (int c = 0; c < 2; ++c) {
      #pragma unroll
      for (int nt = 0; nt < 4; ++nt) {
        int row = nt*16 + qq;
        int col = (c*32 + 8*g) ^ ((row & 7) << 3);
        f16x8 kb = *(const f16x8*)&Kl[cur][row*64 + col];
        sacc[nt] = __builtin_amdgcn_mfma_f32_16x16x32_f16(kb, aq[c], sacc[nt], 0, 0, 0);
      }
    }
    __builtin_amdgcn_s_setprio(0);

    // causal mask (wave-uniform skip: only diagonal tiles mask)
    if (kvs + 63 > qs + wid*16) {
      int qg = qs + wid*16 + qq;
      #pragma unroll
      for (int nt = 0; nt < 4; ++nt)
        #pragma unroll
        for (int r = 0; r < 4; ++r)
          if (kvs + nt*16 + g*4 + r > qg) sacc[nt][r] = -1e30f;
    }

    // per-lane partial max (tree)
    float m0a = fmaxf(fmaxf(sacc[0][0], sacc[0][1]), fmaxf(sacc[0][2], sacc[0][3]));
    float m1a = fmaxf(fmaxf(sacc[1][0], sacc[1][1]), fmaxf(sacc[1][2], sacc[1][3]));
    float m2a = fmaxf(fmaxf(sacc[2][0], sacc[2][1]), fmaxf(sacc[2][2], sacc[2][3]));
    float m3a = fmaxf(fmaxf(sacc[3][0], sacc[3][1]), fmaxf(sacc[3][2], sacc[3][3]));
    float mloc = fmaxf(fmaxf(m0a, m1a), fmaxf(m2a, m3a));

    // defer check on PARTIAL maxes: common path has zero cross-lane ops
    const bool defer = __all(mloc <= m_run + 8.f);   // P bounded by 2^8, f16-safe
    float mnew;
    if (defer) {
      mnew = m_run;
    } else {
      float mf = fmaxf(mloc, __shfl_xor(mloc, 16));
      mf = fmaxf(mf, __shfl_xor(mf, 32));
      mnew = fmaxf(m_run, mf);
      float a = exp2f(m_run - mnew);
      m_run = mnew;
      #pragma unroll
      for (int dt = 0; dt < 4; ++dt) accO[dt] *= a;   // q = qq: per-lane scalar
      accS *= a;
    }

    // P = exp2(S - m) -> f16 B-fragments IN REGISTER (kv = nt*16 + 4g + r)
    f16x4 pb[4];
    #pragma unroll
    for (int nt = 0; nt < 4; ++nt) {
      float p0 = exp2f(sacc[nt][0] - mnew);
      float p1 = exp2f(sacc[nt][1] - mnew);
      float p2 = exp2f(sacc[nt][2] - mnew);
      float p3 = exp2f(sacc[nt][3] - mnew);
      u32x2 w;
      w.x = __builtin_bit_cast(u32, __builtin_amdgcn_cvt_pkrtz(p0, p1));
      w.y = __builtin_bit_cast(u32, __builtin_amdgcn_cvt_pkrtz(p2, p3));
      pb[nt] = __builtin_bit_cast(f16x4, w);
    }

    // O^T += V^T P^T ; l += 1·P^T   (K=16 MFMAs, P never leaves registers)
    __builtin_amdgcn_s_setprio(1);
    #pragma unroll
    for (int nt = 0; nt < 4; ++nt) {
      accS = __builtin_amdgcn_mfma_f32_16x16x16f16(ones4, pb[nt], accS, 0, 0, 0);
      #pragma unroll
      for (int dt = 0; dt < 4; ++dt) {
        int vrow = dt*16 + qq;
        int slot = (2*nt + (g >> 1)) ^ (vrow & 7);
        f16x4 vb = *(const f16x4*)&Vl[cur][vrow*64 + slot*8 + (g & 1)*4];
        accO[dt] = __builtin_amdgcn_mfma_f32_16x16x16f16(vb, pb[nt], accO[dt], 0, 0, 0);
      }
    }
    __builtin_amdgcn_s_setprio(0);
  }

  const float inv = 1.0f / accS[0];
  if (mode == 0) {
    // y[b][t=qs+wid*16+qq][h*64 + dt*16 + g*4 + r], 8B packed stores
    int t = qs + wid*16 + qq;
    #pragma unroll
    for (int dt = 0; dt < 4; ++dt) {
      u32x2 st;
      st.x = (u32)f2h(accO[dt][0]*inv) | ((u32)f2h(accO[dt][1]*inv) << 16);
      st.y = (u32)f2h(accO[dt][2]*inv) | ((u32)f2h(accO[dt][3]*inv) << 16);
      *(u32x2*)(y + ((size_t)(b*NT + t))*NC + h*ND + dt*16 + g*4) = st;
    }
  } else {
    // partial: normalized O (f16) [qlocal][d], m, l (f32) headers
    const int slot = ((bh << 4) + (qtile - 16))*2 + (mode - 1);
    u16* pp = part + (size_t)slot * PSTRIDE;
    float* hd = (float*)(pp + 4096);
    const int rloc = wid*16 + qq;
    #pragma unroll
    for (int dt = 0; dt < 4; ++dt) {
      u32x2 st;
      st.x = (u32)f2h(accO[dt][0]*inv) | ((u32)f2h(accO[dt][1]*inv) << 16);
      st.y = (u32)f2h(accO[dt][2]*inv) | ((u32)f2h(accO[dt][3]*inv) << 16);
      *(u32x2*)(pp + rloc*64 + dt*16 + g*4) = st;
    }
    if (g == 0) { hd[rloc] = m_run; hd[64 + rloc] = accS[0]; }
  }
}

// ---------------- combine two kv-half partials -> y (qtiles 16..31) ----------
__global__ __launch_bounds__(256) void combine_kernel(const u16* __restrict__ part,
                                                      u16* __restrict__ y) {
  const int jj = blockIdx.x;              // qtile = 16 + jj
  const int bh = blockIdx.y;
  const int b = bh >> 4, h = bh & 15;
  const u16* p0 = part + (size_t)(((bh << 4) + jj)*2) * PSTRIDE;
  const u16* p1 = p0 + PSTRIDE;
  const float* h0 = (const float*)(p0 + 4096);
  const float* h1 = (const float*)(p1 + 4096);
  const int tid = threadIdx.x;
  const int d0 = (tid & 7) * 8;
  #pragma unroll
  for (int i = 0; i < 2; ++i) {
    int r = (tid >> 3) + 32*i;
    float m1 = h0[r], l1 = h0[64 + r];
    float m2 = h1[r], l2 = h1[64 + r];
    float mm = fmaxf(m1, m2);
    float w1 = exp2f(m1 - mm) * l1, w2 = exp2f(m2 - mm) * l2;
    float inv = 1.0f / (w1 + w2);
    float a1 = w1 * inv, a2 = w2 * inv;
    f16x8 o1 = *(const f16x8*)&p0[r*64 + d0];
    f16x8 o2 = *(const f16x8*)&p1[r*64 + d0];
    f16x8 out;
    #pragma unroll
    for (int e = 0; e < 8; ++e)
      out[e] = (_Float16)(a1 * (float)o1[e] + a2 * (float)o2[e]);
    int t = (16 + jj)*64 + r;
    *(f16x8*)(y + ((size_t)(b*NT + t))*NC + h*ND + d0) = out;
  }
}

// ---------------- launch ----------------
extern "C" void kernel_launch(void* const* d_in, const int* in_sizes, int n_in,
                              void* d_out, int out_size, void* d_ws, size_t ws_size,
                              hipStream_t stream) {
  const float* x  = (const float*)d_in[0];
  const float* Wq = (const float*)d_in[1];
  const float* Wk = (const float*)d_in[2];
  const float* Wv = (const float*)d_in[3];
  const float* Wp = (const float*)d_in[4];

  u16* xb   = (u16*)d_ws;                       // [4096][1024]; dead after gemm<0> -> partials
  u16* wqkv = xb   + (size_t)NM*NC;             // [3072][1024]; dead after gemm<0>
  u16* wpj  = wqkv + (size_t)3*NC*NC;           // [1024][1024] (needed by gemm<1>)
  u16* qb   = wpj  + (size_t)NC*NC;             // [BH][T][D], pre-scaled log2e/8
  u16* kb   = qb   + (size_t)NM*NC;             // [BH][T][D]
  u16* vtb  = kb   + (size_t)NM*NC;             // [BH][D][T]
  u16* yb   = vtb  + (size_t)NM*NC;             // [4096][1024]
  u16* part = xb;                               // 1024 slots x 9216B = 9.4MB (xb+wqkv dead)
  size_t need = ((size_t)NM*NC*5 + (size_t)4*NC*NC) * sizeof(u16);
  if (ws_size < need) return;                   // fail loudly (output stays zero)

  cvt_kernel<<<NM*NC/4/256, 256, 0, stream>>>(x, xb, NM*NC/4);
  cvtw_kernel<<<4*NC*NC/4/256, 256, 0, stream>>>(Wq, Wk, Wv, Wp, wqkv);

  gemm_bt<0><<<dim3(3*NC/128, NM/128), 256, 0, stream>>>(xb, wqkv, NC, 3*NC,
                                                         qb, kb, vtb, nullptr);
  attn_kernel<<<dim3(NB*NH, 48), 256, 0, stream>>>(qb, kb, vtb, yb, part);
  combine_kernel<<<dim3(16, NB*NH), 256, 0, stream>>>(part, yb);
  gemm_bt<1><<<dim3(NC/128, NM/128), 256, 0, stream>>>(yb, wpj, NC, NC,
                                                       nullptr, nullptr, nullptr,
                                                       (float*)d_out);
}

// Round 12
// 112.025 us; speedup vs baseline: 1.0152x; 1.0152x over previous
//
#include <hip/hip_runtime.h>
#include <stdint.h>

typedef uint16_t u16;
typedef uint32_t u32;
typedef __attribute__((ext_vector_type(8))) _Float16 f16x8;
typedef __attribute__((ext_vector_type(4))) _Float16 f16x4;
typedef __attribute__((ext_vector_type(4))) float f32x4;
typedef __attribute__((ext_vector_type(2))) uint32_t u32x2;

#define NB 2
#define NT 2048
#define NC 1024
#define NH 16
#define ND 64
#define NM (NB*NT)   // 4096 rows of x
#define LOG2E 1.44269504088896340736f
#define PSTRIDE 4352   // u16 elems per partial slot: 64*64 O (4096) + 64 m + 64 l (f32, 256)

__device__ __forceinline__ u16 f2h(float f) {
  _Float16 h = (_Float16)f;   // RNE
  return __builtin_bit_cast(u16, h);
}

// ---------------- f32 -> f16 convert, 4 elems/thread ----------------
__global__ __launch_bounds__(256) void cvt_kernel(const float* __restrict__ src,
                                                  u16* __restrict__ dst, int n4) {
  int i = blockIdx.x * 256 + threadIdx.x;
  if (i >= n4) return;
  float4 v = ((const float4*)src)[i];
  ushort4 o;
  o.x = f2h(v.x); o.y = f2h(v.y); o.z = f2h(v.z); o.w = f2h(v.w);
  ((ushort4*)dst)[i] = o;
}

// 4 weights -> one contiguous f16 region (Wq|Wk|Wv|Wproj)
__global__ __launch_bounds__(256) void cvtw_kernel(const float* __restrict__ w0,
                                                   const float* __restrict__ w1,
                                                   const float* __restrict__ w2,
                                                   const float* __restrict__ w3,
                                                   u16* __restrict__ dst) {
  int i = blockIdx.x * 256 + threadIdx.x;       // 0 .. 4*NC*NC/4
  int which = i >> 18;                          // NC*NC/4 = 262144
  const float* src = (which == 0) ? w0 : (which == 1) ? w1 : (which == 2) ? w2 : w3;
  int j = i & 262143;
  float4 v = ((const float4*)src)[j];
  ushort4 o;
  o.x = f2h(v.x); o.y = f2h(v.y); o.z = f2h(v.z); o.w = f2h(v.w);
  ((ushort4*)dst)[i] = o;
}

// ---------------- async global->LDS 16B ----------------
__device__ __forceinline__ void gload16(const void* g, void* l) {
  __builtin_amdgcn_global_load_lds(
      (const __attribute__((address_space(1))) void*)g,
      (__attribute__((address_space(3))) void*)l, 16, 0, 0);
}

// ---------------- GEMM, both operands k-major (C[m][n] = sum_k A[m][k]*B[n][k]) ---
// Double-buffered staging + XOR-swizzled LDS (conflict-free ds_read_b128).
// EPI 0: QKV epilogue, LDS re-tiled + coalesced 16B stores.
// EPI 1: f32 row-major output.
template<int EPI>
__global__ __launch_bounds__(256) void gemm_bt(const u16* __restrict__ A,
                                               const u16* __restrict__ Bw,
                                               int K, int N,
                                               u16* __restrict__ oq, u16* __restrict__ okk,
                                               u16* __restrict__ ovt,
                                               float* __restrict__ of) {
  __shared__ __align__(16) u16 SH[4*128*64];   // 64 KB: A dbuf | B dbuf
  u16* Al = SH;
  u16* Bl = SH + 2*128*64;
  const int tid = threadIdx.x, lane = tid & 63, wid = tid >> 6;
  const int g = lane >> 4, qq = lane & 15;
  const int wm = wid >> 1, wn = wid & 1;
  const int m0 = blockIdx.y * 128, n0 = blockIdx.x * 128;
  const int srow = lane >> 3;            // row within an 8-row staging issue
  const int scol8 = (lane & 7) ^ srow;   // pre-swizzled 16B-slot in global source

  f32x4 acc[4][4] = {};
  const int nk = K >> 6;

  #pragma unroll
  for (int pp = 0; pp < 4; ++pp) {
    int r = wid*32 + pp*8;
    gload16(A  + (size_t)(m0 + r + srow)*K + scol8*8, &Al[r*64]);
    gload16(Bw + (size_t)(n0 + r + srow)*K + scol8*8, &Bl[r*64]);
  }

  for (int kt = 0; kt < nk; ++kt) {
    const int cur = kt & 1;
    __syncthreads();
    if (kt + 1 < nk) {
      const int k1 = (kt + 1) << 6;
      #pragma unroll
      for (int pp = 0; pp < 4; ++pp) {
        int r = wid*32 + pp*8;
        gload16(A  + (size_t)(m0 + r + srow)*K + k1 + scol8*8, &Al[(cur^1)*8192 + r*64]);
        gload16(Bw + (size_t)(n0 + r + srow)*K + k1 + scol8*8, &Bl[(cur^1)*8192 + r*64]);
      }
    }
    #pragma unroll
    for (int kk = 0; kk < 2; ++kk) {
      f16x8 af[4], bfr[4];
      #pragma unroll
      for (int mt = 0; mt < 4; ++mt) {
        int row = wm*64 + mt*16 + qq;
        af[mt] = *(const f16x8*)&Al[cur*8192 + row*64 + (((kk*4 + g) ^ (qq & 7))*8)];
      }
      #pragma unroll
      for (int nt = 0; nt < 4; ++nt) {
        int row = wn*64 + nt*16 + qq;
        bfr[nt] = *(const f16x8*)&Bl[cur*8192 + row*64 + (((kk*4 + g) ^ (qq & 7))*8)];
      }
      #pragma unroll
      for (int mt = 0; mt < 4; ++mt)
        #pragma unroll
        for (int nt = 0; nt < 4; ++nt)
          acc[mt][nt] = __builtin_amdgcn_mfma_f32_16x16x32_f16(af[mt], bfr[nt], acc[mt][nt], 0, 0, 0);
    }
  }

  if (EPI == 0) {
    __syncthreads();
    u16* reg = SH + wid*4096;
    const int sel = n0 >> 10;
    const int h = ((n0 & 1023) >> 6) + wn;
    const int bq = m0 >> 11;

    if (sel < 2) {
      const float scale = (sel == 0) ? 0.125f*LOG2E : 1.0f;
      #pragma unroll
      for (int mt = 0; mt < 4; ++mt)
        #pragma unroll
        for (int r = 0; r < 4; ++r) {
          int mloc = mt*16 + g*4 + r;
          #pragma unroll
          for (int nt = 0; nt < 4; ++nt) {
            int d = nt*16 + qq;
            reg[mloc*64 + (d ^ (g << 4))] = f2h(acc[mt][nt][r] * scale);
          }
        }
      u16* dst = (sel == 0) ? oq : okk;
      const int slot = lane & 7;
      #pragma unroll
      for (int i = 0; i < 8; ++i) {
        int row = i*8 + (lane >> 3);
        int physslot = slot ^ (((row >> 2) & 3) << 1);
        f16x8 vvv = *(const f16x8*)&reg[row*64 + physslot*8];
        int m = m0 + wm*64 + row;
        int t = m & (NT-1);
        *(f16x8*)(dst + (((size_t)(bq*NH + h)*NT + t)*ND) + slot*8) = vvv;
      }
    } else {
      #pragma unroll
      for (int nt = 0; nt < 4; ++nt) {
        int d = nt*16 + qq;
        int f = (d & 7) << 3;
        #pragma unroll
        for (int mt = 0; mt < 4; ++mt)
          #pragma unroll
          for (int rp = 0; rp < 2; ++rp) {
            int r = rp*2;
            int mloc = mt*16 + g*4 + r;
            u32 pk = (u32)f2h(acc[mt][nt][r]) | ((u32)f2h(acc[mt][nt][r+1]) << 16);
            *(u32*)&reg[d*64 + (mloc ^ f)] = pk;
          }
      }
      const int slot = lane & 7;
      const int t0 = m0 + wm*64;
      #pragma unroll
      for (int i = 0; i < 8; ++i) {
        int d = i*8 + (lane >> 3);
        int physslot = slot ^ (d & 7);
        f16x8 vvv = *(const f16x8*)&reg[d*64 + physslot*8];
        int t = (t0 & (NT-1)) + slot*8;
        *(f16x8*)(ovt + ((size_t)(bq*NH + h)*ND + d)*NT + t) = vvv;
      }
    }
  } else {
    #pragma unroll
    for (int mt = 0; mt < 4; ++mt)
      #pragma unroll
      for (int r = 0; r < 4; ++r) {
        int m = m0 + wm*64 + mt*16 + g*4 + r;
        #pragma unroll
        for (int nt = 0; nt < 4; ++nt) {
          int n = n0 + wn*64 + nt*16 + qq;
          of[(size_t)m*N + n] = acc[mt][nt][r];
        }
      }
  }
}

// ---------------- flash attention: fine-grained split-kv (chunks <= 12 tiles) -
// Work item = (qtile, ks, kc, mode). mode 0 = direct y write (qtiles 0..11);
// mode p>0 = partial slot p-1 (normalized O f16 + m,l f32 headers -> ws).
// qtiles 12..23 -> 2 chunks, 24..31 -> 3 chunks (balanced sizes, <=12).
// 60 items/bh, dispatched DESCENDING size -> greedy slot-refill ~ LPT.
// Compute per R10: swapped QK^T + in-register P -> K=16 PV MFMAs.
#define IT(q,s,c,m) ((u32)(q) | ((u32)(s)<<8) | ((u32)(c)<<16) | ((u32)(m)<<24))
__global__ __launch_bounds__(256, 5) void attn_kernel(const u16* __restrict__ q,
                                                      const u16* __restrict__ k,
                                                      const u16* __restrict__ vt,
                                                      u16* __restrict__ y,
                                                      u16* __restrict__ part) {
  static const u32 items[60] = {
    // kc = 12
    IT(11,0,12,0),  IT(22,0,12,21), IT(23,0,12,23), IT(23,12,12,24),
    // kc = 11
    IT(10,0,11,0),  IT(20,0,11,17), IT(21,0,11,19), IT(21,11,11,20),
    IT(22,12,11,22),IT(30,0,11,43), IT(31,0,11,46), IT(31,11,11,47),
    // kc = 10
    IT(9,0,10,0),   IT(18,0,10,13), IT(19,0,10,15), IT(19,10,10,16),
    IT(20,11,10,18),IT(27,0,10,34), IT(28,0,10,37), IT(28,10,10,38),
    IT(29,0,10,40), IT(29,10,10,41),IT(29,20,10,42),IT(30,11,10,44),
    IT(30,21,10,45),IT(31,22,10,48),
    // kc = 9
    IT(8,0,9,0),    IT(16,0,9,9),   IT(17,0,9,11),  IT(17,9,9,12),
    IT(18,10,9,14), IT(24,0,9,25),  IT(25,0,9,28),  IT(25,9,9,29),
    IT(26,0,9,31),  IT(26,9,9,32),  IT(26,18,9,33), IT(27,10,9,35),
    IT(27,19,9,36), IT(28,20,9,39),
    // kc = 8
    IT(7,0,8,0),    IT(14,0,8,5),   IT(15,0,8,7),   IT(15,8,8,8),
    IT(16,9,8,10),  IT(24,9,8,26),  IT(24,17,8,27), IT(25,18,8,30),
    // kc = 7
    IT(6,0,7,0),    IT(12,0,7,1),   IT(13,0,7,3),   IT(13,7,7,4),
    IT(14,8,7,6),
    // kc = 6
    IT(5,0,6,0),    IT(12,7,6,2),
    // kc <= 5
    IT(4,0,5,0), IT(3,0,4,0), IT(2,0,3,0), IT(1,0,2,0), IT(0,0,1,0)
  };
  __shared__ __align__(16) u16 Kl[2][64*64];
  __shared__ __align__(16) u16 Vl[2][64*64];
  const int tid = threadIdx.x, lane = tid & 63, wid = tid >> 6;
  const int g = lane >> 4, qq = lane & 15;
  const int bh = blockIdx.x;
  const u32 it = items[blockIdx.y];
  const int qtile = it & 255;
  const int ks = (it >> 8) & 255;
  const int kc = (it >> 16) & 255;
  const int mode = it >> 24;
  const int qs = qtile * 64;
  const u16* qp = q  + (size_t)bh*NT*ND;
  const u16* kp = k  + (size_t)bh*NT*ND;
  const u16* vp = vt + (size_t)bh*ND*NT;
  const int b = bh >> 4, h = bh & 15;
  const int srow = lane >> 3;
  const int scol8 = (lane & 7) ^ (srow & 7);  // pre-swizzled 16B-slot in global source

  // Q B-fragment in registers (col q = qs + wid*16 + qq)
  f16x8 aq[2];
  {
    int t = qs + wid*16 + qq;
    #pragma unroll
    for (int c = 0; c < 2; ++c)
      aq[c] = *(const f16x8*)(qp + (size_t)t*ND + c*32 + 8*g);
  }

  f16x4 ones4;
  #pragma unroll
  for (int i = 0; i < 4; ++i) ones4[i] = (_Float16)1.0f;

  f32x4 accO[4] = {};               // O[q = qq][d = dt*16 + g*4 + r]
  f32x4 accS = {};                  // l[q = qq] (ones-MFMA; all 4 regs equal)
  float m_run = -1e30f;             // per-lane, q = qq

  // prologue: stage kv tile ks into buf 0
  #pragma unroll
  for (int pp = 0; pp < 2; ++pp) {
    int issue = wid*2 + pp;
    int row = issue*8 + srow;
    gload16(kp + (size_t)(ks*64 + row)*ND + scol8*8, &Kl[0][issue*512]);
    gload16(vp + (size_t)row*NT + ks*64 + scol8*8, &Vl[0][issue*512]);
  }

  for (int kt = ks; kt < ks + kc; ++kt) {
    const int kvs = kt*64;
    const int cur = (kt - ks) & 1;
    __syncthreads();                // stage(kt) drained; buf cur^1 free

    if (kt + 1 < ks + kc) {         // stage next tile under compute(kt)
      const int kvs2 = kvs + 64;
      #pragma unroll
      for (int pp = 0; pp < 2; ++pp) {
        int issue = wid*2 + pp;
        int row = issue*8 + srow;
        gload16(kp + (size_t)(kvs2 + row)*ND + scol8*8, &Kl[cur^1][issue*512]);
        gload16(vp + (size_t)row*NT + kvs2 + scol8*8, &Vl[cur^1][issue*512]);
      }
    }

    // S^T = K Q^T: sacc[nt][r]: kv = kvs+nt*16+g*4+r, q = qs+wid*16+qq
    f32x4 sacc[4] = {};
    __builtin_amdgcn_s_setprio(1);
    #pragma unroll
    for (int c = 0; c < 2; ++c) {
      #pragma unroll
      for (int nt = 0; nt < 4; ++nt) {
        int row = nt*16 + qq;
        int col = (c*32 + 8*g) ^ ((row & 7) << 3);
        f16x8 kb = *(const f16x8*)&Kl[cur][row*64 + col];
        sacc[nt] = __builtin_amdgcn_mfma_f32_16x16x32_f16(kb, aq[c], sacc[nt], 0, 0, 0);
      }
    }
    __builtin_amdgcn_s_setprio(0);

    // causal mask (wave-uniform skip: only diagonal tiles mask)
    if (kvs + 63 > qs + wid*16) {
      int qg = qs + wid*16 + qq;
      #pragma unroll
      for (int nt = 0; nt < 4; ++nt)
        #pragma unroll
        for (int r = 0; r < 4; ++r)
          if (kvs + nt*16 + g*4 + r > qg) sacc[nt][r] = -1e30f;
    }

    // per-lane partial max (tree)
    float m0a = fmaxf(fmaxf(sacc[0][0], sacc[0][1]), fmaxf(sacc[0][2], sacc[0][3]));
    float m1a = fmaxf(fmaxf(sacc[1][0], sacc[1][1]), fmaxf(sacc[1][2], sacc[1][3]));
    float m2a = fmaxf(fmaxf(sacc[2][0], sacc[2][1]), fmaxf(sacc[2][2], sacc[2][3]));
    float m3a = fmaxf(fmaxf(sacc[3][0], sacc[3][1]), fmaxf(sacc[3][2], sacc[3][3]));
    float mloc = fmaxf(fmaxf(m0a, m1a), fmaxf(m2a, m3a));

    // defer check on PARTIAL maxes: common path has zero cross-lane ops
    const bool defer = __all(mloc <= m_run + 8.f);   // P bounded by 2^8, f16-safe
    float mnew;
    if (defer) {
      mnew = m_run;
    } else {
      float mf = fmaxf(mloc, __shfl_xor(mloc, 16));
      mf = fmaxf(mf, __shfl_xor(mf, 32));
      mnew = fmaxf(m_run, mf);
      float a = exp2f(m_run - mnew);
      m_run = mnew;
      #pragma unroll
      for (int dt = 0; dt < 4; ++dt) accO[dt] *= a;   // q = qq: per-lane scalar
      accS *= a;
    }

    // P = exp2(S - m) -> f16 B-fragments IN REGISTER (kv = nt*16 + 4g + r)
    f16x4 pb[4];
    #pragma unroll
    for (int nt = 0; nt < 4; ++nt) {
      float p0 = exp2f(sacc[nt][0] - mnew);
      float p1 = exp2f(sacc[nt][1] - mnew);
      float p2 = exp2f(sacc[nt][2] - mnew);
      float p3 = exp2f(sacc[nt][3] - mnew);
      u32x2 w;
      w.x = __builtin_bit_cast(u32, __builtin_amdgcn_cvt_pkrtz(p0, p1));
      w.y = __builtin_bit_cast(u32, __builtin_amdgcn_cvt_pkrtz(p2, p3));
      pb[nt] = __builtin_bit_cast(f16x4, w);
    }

    // O^T += V^T P^T ; l += 1·P^T   (K=16 MFMAs, P never leaves registers)
    __builtin_amdgcn_s_setprio(1);
    #pragma unroll
    for (int nt = 0; nt < 4; ++nt) {
      accS = __builtin_amdgcn_mfma_f32_16x16x16f16(ones4, pb[nt], accS, 0, 0, 0);
      #pragma unroll
      for (int dt = 0; dt < 4; ++dt) {
        int vrow = dt*16 + qq;
        int slot = (2*nt + (g >> 1)) ^ (vrow & 7);
        f16x4 vb = *(const f16x4*)&Vl[cur][vrow*64 + slot*8 + (g & 1)*4];
        accO[dt] = __builtin_amdgcn_mfma_f32_16x16x16f16(vb, pb[nt], accO[dt], 0, 0, 0);
      }
    }
    __builtin_amdgcn_s_setprio(0);
  }

  const float inv = 1.0f / accS[0];
  if (mode == 0) {
    // y[b][t=qs+wid*16+qq][h*64 + dt*16 + g*4 + r], 8B packed stores
    int t = qs + wid*16 + qq;
    #pragma unroll
    for (int dt = 0; dt < 4; ++dt) {
      u32x2 st;
      st.x = (u32)f2h(accO[dt][0]*inv) | ((u32)f2h(accO[dt][1]*inv) << 16);
      st.y = (u32)f2h(accO[dt][2]*inv) | ((u32)f2h(accO[dt][3]*inv) << 16);
      *(u32x2*)(y + ((size_t)(b*NT + t))*NC + h*ND + dt*16 + g*4) = st;
    }
  } else {
    // partial: normalized O (f16) [qlocal][d], m, l (f32) headers
    const int slot = bh*48 + (mode - 1);
    u16* pp = part + (size_t)slot * PSTRIDE;
    float* hd = (float*)(pp + 4096);
    const int rloc = wid*16 + qq;
    #pragma unroll
    for (int dt = 0; dt < 4; ++dt) {
      u32x2 st;
      st.x = (u32)f2h(accO[dt][0]*inv) | ((u32)f2h(accO[dt][1]*inv) << 16);
      st.y = (u32)f2h(accO[dt][2]*inv) | ((u32)f2h(accO[dt][3]*inv) << 16);
      *(u32x2*)(pp + rloc*64 + dt*16 + g*4) = st;
    }
    if (g == 0) { hd[rloc] = m_run; hd[64 + rloc] = accS[0]; }
  }
}

// ---------------- combine 2-3 kv-chunk partials -> y (qtiles 12..31) ----------
// pslot base: qtile 12..23 -> (qtile-12)*2 (2 chunks); 24..31 -> 24+(qtile-24)*3.
__global__ __launch_bounds__(256) void combine_kernel(const u16* __restrict__ part,
                                                      u16* __restrict__ y) {
  const int qtile = 12 + blockIdx.x;      // 12..31
  const int bh = blockIdx.y;
  const int b = bh >> 4, h = bh & 15;
  const int nc = (qtile < 24) ? 2 : 3;
  const int pbase = (qtile < 24) ? (qtile - 12)*2 : 24 + (qtile - 24)*3;
  const u16* p0 = part + (size_t)(bh*48 + pbase) * PSTRIDE;
  const int tid = threadIdx.x;
  const int d0 = (tid & 7) * 8;
  #pragma unroll
  for (int i = 0; i < 2; ++i) {
    int r = (tid >> 3) + 32*i;
    float m0 = ((const float*)(p0 + 4096))[r];
    float l0 = ((const float*)(p0 + 4096))[64 + r];
    float m1 = ((const float*)(p0 + PSTRIDE + 4096))[r];
    float l1 = ((const float*)(p0 + PSTRIDE + 4096))[64 + r];
    float m2 = (nc == 3) ? ((const float*)(p0 + 2*PSTRIDE + 4096))[r]      : -1e30f;
    float l2 = (nc == 3) ? ((const float*)(p0 + 2*PSTRIDE + 4096))[64 + r] : 0.f;
    float mm = fmaxf(fmaxf(m0, m1), m2);
    float w0 = exp2f(m0 - mm) * l0;
    float w1 = exp2f(m1 - mm) * l1;
    float w2 = exp2f(m2 - mm) * l2;
    float inv = 1.0f / (w0 + w1 + w2);
    float a0 = w0 * inv, a1 = w1 * inv, a2 = w2 * inv;
    f16x8 o0 = *(const f16x8*)&p0[r*64 + d0];
    f16x8 o1 = *(const f16x8*)&p0[PSTRIDE + r*64 + d0];
    f16x8 o2 = *(const f16x8*)&p0[2*PSTRIDE + r*64 + d0];   // a2==0 when nc==2
    f16x8 out;
    #pragma unroll
    for (int e = 0; e < 8; ++e)
      out[e] = (_Float16)(a0*(float)o0[e] + a1*(float)o1[e] + a2*(float)o2[e]);
    int t = qtile*64 + r;
    *(f16x8*)(y + ((size_t)(b*NT + t))*NC + h*ND + d0) = out;
  }
}

// ---------------- launch ----------------
extern "C" void kernel_launch(void* const* d_in, const int* in_sizes, int n_in,
                              void* d_out, int out_size, void* d_ws, size_t ws_size,
                              hipStream_t stream) {
  const float* x  = (const float*)d_in[0];
  const float* Wq = (const float*)d_in[1];
  const float* Wk = (const float*)d_in[2];
  const float* Wv = (const float*)d_in[3];
  const float* Wp = (const float*)d_in[4];

  u16* xb   = (u16*)d_ws;                       // [4096][1024]; dead after gemm<0> -> partials
  u16* wqkv = xb   + (size_t)NM*NC;             // [3072][1024]; dead after gemm<0>
  u16* wpj  = wqkv + (size_t)3*NC*NC;           // [1024][1024] (needed by gemm<1>)
  u16* qb   = wpj  + (size_t)NC*NC;             // [BH][T][D], pre-scaled log2e/8
  u16* kb   = qb   + (size_t)NM*NC;             // [BH][T][D]
  u16* vtb  = kb   + (size_t)NM*NC;             // [BH][D][T]
  u16* yb   = vtb  + (size_t)NM*NC;             // [4096][1024]
  u16* part = xb;                               // 1536 slots x 8704B = 13.4MB (xb+wqkv dead = 14.7MB)
  size_t need = ((size_t)NM*NC*5 + (size_t)4*NC*NC) * sizeof(u16);
  if (ws_size < need) return;                   // fail loudly (output stays zero)

  cvt_kernel<<<NM*NC/4/256, 256, 0, stream>>>(x, xb, NM*NC/4);
  cvtw_kernel<<<4*NC*NC/4/256, 256, 0, stream>>>(Wq, Wk, Wv, Wp, wqkv);

  gemm_bt<0><<<dim3(3*NC/128, NM/128), 256, 0, stream>>>(xb, wqkv, NC, 3*NC,
                                                         qb, kb, vtb, nullptr);
  attn_kernel<<<dim3(NB*NH, 60), 256, 0, stream>>>(qb, kb, vtb, yb, part);
  combine_kernel<<<dim3(20, NB*NH), 256, 0, stream>>>(part, yb);
  gemm_bt<1><<<dim3(NC/128, NM/128), 256, 0, stream>>>(yb, wpj, NC, NC,
                                                       nullptr, nullptr, nullptr,
                                                       (float*)d_out);
}